// Round 4
// baseline (160.992 us; speedup 1.0000x reference)
//
#include <hip/hip_runtime.h>

// ---------------------------------------------------------------------------
// GalerkinAttention on MI355X (gfx950), round 4: 256x256 8-wave deep-pipelined
// GEMM (counted-vmcnt phase schedule, T2+T3+T4+T5) for K1 and K4.
//
// Shapes: B=4, N=8192, D=512, H=8, Dh=64, BN_rows=32768.
// Algebra: y = x @ M_b^T + b_out,
//   M_b[d'][d] = sum_h W_out[d',h-blk] . P_bh . W_q[h-blk,d] / n
//
// Pipeline:
//   K0 : convert x, W_qkv, W_out to bf16
//   K1 : per (256-row-tile, head-pair): kv = x @ W^T (256x256, BK=64, 8 waves,
//        4-phase/K-tile counted-vmcnt pipeline); epilogue: in-register
//        per-head LN -> kn/vn to LDS (16B-XOR transpose) -> P MFMA -> atomics
//   K3a: Gt[b][d][h*64+dv] = sum_dh P[bh][dh][dv] * Wqkv[h*64+dh][d] / 8192
//   K3b: M_b = Wout_bf16 @ Gt_b (bf16 GEMM, 128^2 structure - tiny)
//   K4 : y = xb @ M_b^T + b_out (256x256 pipeline, fp32 store)
//
// MFMA 16x16x32 bf16 (verified rounds 1-3):
//   A frag: lane l holds A[row=l&15][k = ks*32 + (l>>4)*8 + e]
//   B frag: lane l holds B[col=l&15][same k]
//   C/D   : lane l reg r -> C[row=(l>>4)*4+r][col=l&15]
//
// Main-loop LDS: A/B tiles [256][64] shorts, 8-short XOR swizzle
//   (stage source col pre-swizzled by ((tid&7)^((tid>>3)&7))*8; read col
//    ^ ((c16&7)<<3)) -- bank-conflict-free (round-2 verified, PMC=0).
// vmcnt ledger (2 loads per staged half, FIFO):
//   tile T stages A(T+1)@ph0-1, B(T+2)@ph2-3; at end of T outstanding =
//   [B(T+1):4, A(T+1):4, B(T+2):4] -> vmcnt(4) drains B(T+1),A(T+1),
//   leaves B(T+2) in flight. Tail: end of kt=6 -> vmcnt(0). Never 0 before.
// ---------------------------------------------------------------------------

typedef __attribute__((ext_vector_type(8))) short bf16x8;
typedef __attribute__((ext_vector_type(4))) float f32x4;
typedef __attribute__((ext_vector_type(4))) unsigned short u16x4;

__device__ __forceinline__ unsigned short f2bf(float f) {
  unsigned int u = __builtin_bit_cast(unsigned int, f);
  u += 0x7FFFu + ((u >> 16) & 1u);   // RNE
  return (unsigned short)(u >> 16);
}

__device__ __forceinline__ f32x4 mfma16(bf16x8 a, bf16x8 b, f32x4 c) {
  return __builtin_amdgcn_mfma_f32_16x16x32_bf16(a, b, c, 0, 0, 0);
}

__device__ __forceinline__ void gload16(const void* g, void* l) {
  __builtin_amdgcn_global_load_lds(
      (const __attribute__((address_space(1))) void*)g,
      (__attribute__((address_space(3))) void*)l, 16, 0, 0);
}

// ------------------------------- K0: convert -------------------------------
__global__ void k_cvt_bf16(const float* __restrict__ src,
                           unsigned short* __restrict__ dst, int n4) {
  int i = blockIdx.x * blockDim.x + threadIdx.x;
  if (i < n4) {
    float4 v = ((const float4*)src)[i];
    u16x4 o;
    o[0] = f2bf(v.x); o[1] = f2bf(v.y); o[2] = f2bf(v.z); o[3] = f2bf(v.w);
    ((u16x4*)dst)[i] = o;
  }
}

// ---------------- 256x256 (K=512) 8-wave deep-pipelined loop ----------------
// LDS map (shorts): LA0 [0,16K), LA1 [16K,32K), LB0 [32K,48K), LB1 [48K,64K)
// pA[i]/pB[i]: per-thread staging ptr for tile-rows i*64+(tid>>3), k=0,
// source column pre-swizzled. acc[8][4] must be zero-init by caller.
__device__ __forceinline__ void gemm256_loop(
    const unsigned short* const pA[4], const unsigned short* const pB[4],
    unsigned short* L, int tid, f32x4 acc[8][4])
{
  const int l = tid & 63, w = tid >> 6;
  const int wr = w >> 2, wc = w & 3;
  const int g = l >> 4, c16 = l & 15;
  const int wslot = w * 512;            // per-wave 1KB slice of a stage instr
  unsigned short* LA[2] = {L, L + 16384};
  unsigned short* LB[2] = {L + 32768, L + 49152};

  // prologue: B(0), A(0), B(1)  -> 12 loads; drain to 4 (B(1) stays in flight)
#pragma unroll
  for (int i = 0; i < 4; ++i) gload16(pB[i], LB[0] + i * 4096 + wslot);
#pragma unroll
  for (int i = 0; i < 4; ++i) gload16(pA[i], LA[0] + i * 4096 + wslot);
#pragma unroll
  for (int i = 0; i < 4; ++i) gload16(pB[i] + 64, LB[1] + i * 4096 + wslot);
  asm volatile("s_waitcnt vmcnt(4)");
  __builtin_amdgcn_s_barrier();

  for (int kt = 0; kt < 8; ++kt) {
    const unsigned short* Ab = LA[kt & 1];
    const unsigned short* Bb = LB[kt & 1];
    bf16x8 bfr[4][2];
#pragma unroll
    for (int ph = 0; ph < 4; ++ph) {
      // ---- ds reads for this phase (B once per tile, A per phase)
      if (ph == 0) {
#pragma unroll
        for (int ni = 0; ni < 4; ++ni)
#pragma unroll
          for (int ks = 0; ks < 2; ++ks)
            bfr[ni][ks] = *(const bf16x8*)
                &Bb[(wc * 64 + ni * 16 + c16) * 64 +
                    ((ks * 32 + g * 8) ^ ((c16 & 7) << 3))];
      }
      bf16x8 af[2][2];
#pragma unroll
      for (int d = 0; d < 2; ++d)
#pragma unroll
        for (int ks = 0; ks < 2; ++ks)
          af[d][ks] = *(const bf16x8*)
              &Ab[(wr * 128 + (ph * 2 + d) * 16 + c16) * 64 +
                  ((ks * 32 + g * 8) ^ ((c16 & 7) << 3))];
      // ---- stage one half-tile (2 x gload16)
      if (ph < 2) {
        if (kt < 7) {
#pragma unroll
          for (int i = 0; i < 2; ++i)
            gload16(pA[ph * 2 + i] + (kt + 1) * 64,
                    LA[(kt + 1) & 1] + (ph * 2 + i) * 4096 + wslot);
        }
      } else {
        if (kt < 6) {
#pragma unroll
          for (int i = 0; i < 2; ++i)
            gload16(pB[(ph - 2) * 2 + i] + (kt + 2) * 64,
                    LB[kt & 1] + ((ph - 2) * 2 + i) * 4096 + wslot);
        }
      }
      __builtin_amdgcn_s_barrier();
      asm volatile("s_waitcnt lgkmcnt(0)");
      __builtin_amdgcn_sched_barrier(0);
      __builtin_amdgcn_s_setprio(1);
#pragma unroll
      for (int d = 0; d < 2; ++d)
#pragma unroll
        for (int ni = 0; ni < 4; ++ni)
#pragma unroll
          for (int ks = 0; ks < 2; ++ks)
            acc[ph * 2 + d][ni] = mfma16(af[d][ks], bfr[ni][ks],
                                         acc[ph * 2 + d][ni]);
      __builtin_amdgcn_s_setprio(0);
      if (ph == 3) {
        if (kt < 6)       { asm volatile("s_waitcnt vmcnt(4)"); }
        else if (kt == 6) { asm volatile("s_waitcnt vmcnt(0)"); }
      }
      __builtin_amdgcn_s_barrier();
    }
  }
}

// ---------------- K1: kv GEMM + LN + fused P-accumulation -------------------
// 1D grid 512 blocks (XCD-swizzled) -> (rt 0..127, ct 0..3); 512 threads.
// ct owns head pair (2ct, 2ct+1); wave quadrant wc: 0=k h0, 1=v h0, 2=k h1,
// 3=v h1 (64 cols each = one LayerNorm group).
__launch_bounds__(512, 2)
__global__ void k1_kvp(const unsigned short* __restrict__ xb,
                       const unsigned short* __restrict__ wqkvb,
                       const float* __restrict__ gK, const float* __restrict__ bK,
                       const float* __restrict__ gV, const float* __restrict__ bV,
                       float* __restrict__ P) {
  __shared__ __align__(16) unsigned short L[65536];   // 128 KB
  const int bid = (int)blockIdx.x;
  const int wgid = (bid & 7) * 64 + (bid >> 3);       // bijective (512%8==0)
  const int rt = wgid >> 2, ct = wgid & 3;
  const int tid = (int)threadIdx.x;
  const int l = tid & 63, w = tid >> 6;
  const int wr = w >> 2, wc = w & 3;
  const int g = l >> 4, c16 = l & 15;
  const int row0 = rt * 256;
  const int swzc = ((tid & 7) ^ ((tid >> 3) & 7)) * 8;
  const int r8 = tid >> 3;

  const unsigned short* pA[4];
  const unsigned short* pB[4];
#pragma unroll
  for (int i = 0; i < 4; ++i) {
    pA[i] = xb + (row0 + i * 64 + r8) * 512 + swzc;
    // tile col c = i*64 + r8; quadrant i: k/v of head 2ct+(i>>1)
    const int wrow = 512 + (i & 1) * 512 + (2 * ct + (i >> 1)) * 64 + r8;
    pB[i] = wqkvb + wrow * 512 + swzc;
  }

  f32x4 acc[8][4] = {};
  gemm256_loop(pA, pB, L, tid, acc);

  // ---- per-head LayerNorm; kn/vn -> LDS quadrants ([64 d][256 n], 16B-XOR)
  const int h = 2 * ct + (wc >> 1);
  const bool isV = wc & 1;
  const float* gamma = isV ? gV : gK;
  const float* beta  = isV ? bV : bK;
  float gm[4], bt[4];
#pragma unroll
  for (int ni = 0; ni < 4; ++ni) {
    gm[ni] = gamma[h * 64 + ni * 16 + c16];
    bt[ni] = beta[h * 64 + ni * 16 + c16];
  }
  unsigned short* Lq = L + wc * 16384;
#pragma unroll
  for (int mi = 0; mi < 8; ++mi) {
    float mean4[4], rs4[4];
#pragma unroll
    for (int r = 0; r < 4; ++r) {
      float a0 = acc[mi][0][r], a1 = acc[mi][1][r];
      float a2 = acc[mi][2][r], a3 = acc[mi][3][r];
      float s1 = a0 + a1 + a2 + a3;
      float s2 = a0 * a0 + a1 * a1 + a2 * a2 + a3 * a3;
#pragma unroll
      for (int m = 1; m <= 8; m <<= 1) {   // reduce over 16-lane col group
        s1 += __shfl_xor(s1, m, 64);
        s2 += __shfl_xor(s2, m, 64);
      }
      const float mean = s1 * (1.0f / 64.0f);
      const float var = s2 * (1.0f / 64.0f) - mean * mean;
      mean4[r] = mean;
      rs4[r] = rsqrtf(var + 1e-5f);
    }
    const int n0 = wr * 128 + mi * 16 + g * 4;
#pragma unroll
    for (int ni = 0; ni < 4; ++ni) {
      u16x4 o;
#pragma unroll
      for (int r = 0; r < 4; ++r)
        o[r] = f2bf((acc[mi][ni][r] - mean4[r]) * rs4[r] * gm[ni] + bt[ni]);
      // phys8 = (n>>3) ^ (d&15); d&15 == c16
      *(u16x4*)&Lq[(ni * 16 + c16) * 256 + (((n0 >> 3) ^ c16) << 3) + (n0 & 7)] = o;
    }
  }
  __syncthreads();

  // ---- P-partial: waves 0-3 -> head 2ct, waves 4-7 -> head 2ct+1;
  //      wave strip (w&3) covers dh rows strip*16..+15, all 64 dv, n=256
  const int hh = w >> 2;
  const int strip = w & 3;
  const unsigned short* Kq = L + (hh * 2) * 16384;
  const unsigned short* Vq = L + (hh * 2 + 1) * 16384;
  f32x4 pacc[4] = {};
#pragma unroll
  for (int ks = 0; ks < 8; ++ks) {
    const int grp = ((ks * 4 + g) ^ c16) << 3;
    bf16x8 af = *(const bf16x8*)&Kq[(strip * 16 + c16) * 256 + grp];
#pragma unroll
    for (int ni = 0; ni < 4; ++ni) {
      bf16x8 bv = *(const bf16x8*)&Vq[(ni * 16 + c16) * 256 + grp];
      pacc[ni] = mfma16(af, bv, pacc[ni]);
    }
  }
  const int bh = (row0 >> 13) * 8 + 2 * ct + hh;
  float* Pp = P + bh * 4096;
#pragma unroll
  for (int ni = 0; ni < 4; ++ni)
#pragma unroll
    for (int r = 0; r < 4; ++r)
      atomicAdd(&Pp[(strip * 16 + g * 4 + r) * 64 + ni * 16 + c16], pacc[ni][r]);
}

// ------------- K3a: Gt[b][d][h*64+dv] = sum_dh P[bh][dh][dv]*Wq[h*64+dh][d]/n
__launch_bounds__(256)
__global__ void k3a_g(const float* __restrict__ Wqkv,
                      const float* __restrict__ P,
                      unsigned short* __restrict__ Gt) {
  __shared__ float Pl[64 * 64];
  const int bh = blockIdx.x, dd = blockIdx.y;
  const int b = bh >> 3, h = bh & 7;
  const int t = (int)threadIdx.x;
  for (int i = t; i < 1024; i += 256)
    ((float4*)Pl)[i] = ((const float4*)(P + bh * 4096))[i];
  __syncthreads();

  const int qg = t >> 6, dl = t & 63;
  const int d = dd * 64 + dl;
  float acc[16] = {};
  for (int dh = 0; dh < 64; ++dh) {
    const float wq = Wqkv[(h * 64 + dh) * 512 + d];
    const float* pr = &Pl[dh * 64 + qg * 16];
#pragma unroll
    for (int i = 0; i < 16; ++i) acc[i] += pr[i] * wq;
  }
  unsigned short* go = &Gt[(b * 512 + d) * 512 + h * 64 + qg * 16];
#pragma unroll
  for (int i = 0; i < 16; ++i) go[i] = f2bf(acc[i] * (1.0f / 8192.0f));
}

// ----------- K3b: M_b[d'][d] = sum_e Wout[d'][e] * Gt_b[d][e] ---------------
// tiny (4 GEMMs of 512x512x512); keep round-3 128^2 structure
__device__ __forceinline__ void stage_tile128(const unsigned short* pa,
                                              const unsigned short* pb,
                                              unsigned short* As, unsigned short* Bs,
                                              int w) {
#pragma unroll
  for (int j = 0; j < 4; ++j) {
    gload16(pa + j * 8 * 512, As + w * 2048 + j * 512);
    gload16(pb + j * 8 * 512, Bs + w * 2048 + j * 512);
  }
}

__device__ __forceinline__ void compute_tile128(const unsigned short* As,
                                                const unsigned short* Bs,
                                                int wr, int wc, int g, int c16,
                                                f32x4 acc[4][4]) {
#pragma unroll
  for (int ks = 0; ks < 2; ++ks) {
    const int kcol = (ks * 32 + g * 8) ^ ((c16 & 7) << 3);
    bf16x8 af[4], bfv[4];
#pragma unroll
    for (int mi = 0; mi < 4; ++mi)
      af[mi] = *(const bf16x8*)&As[(wr * 64 + mi * 16 + c16) * 64 + kcol];
#pragma unroll
    for (int ni = 0; ni < 4; ++ni)
      bfv[ni] = *(const bf16x8*)&Bs[(wc * 64 + ni * 16 + c16) * 64 + kcol];
#pragma unroll
    for (int mi = 0; mi < 4; ++mi)
#pragma unroll
      for (int ni = 0; ni < 4; ++ni)
        acc[mi][ni] = mfma16(af[mi], bfv[ni], acc[mi][ni]);
  }
}

__launch_bounds__(256)
__global__ void k3b_m(const unsigned short* __restrict__ wob,
                      const unsigned short* __restrict__ Gt,
                      unsigned short* __restrict__ Mb) {
  __shared__ __align__(16) unsigned short As[2][8192];
  __shared__ __align__(16) unsigned short Bs[2][8192];
  const int rt = blockIdx.x, ct = blockIdx.y, b = blockIdx.z;
  const int tid = (int)threadIdx.x;
  const int l = tid & 63, w = tid >> 6;
  const int wr = w >> 1, wc = w & 1;
  const int g = l >> 4, c16 = l & 15;
  const int row0 = rt * 128, col0 = ct * 128;
  const int swz = ((l & 7) ^ (l >> 3)) * 8;

  const unsigned short* gsA = wob + (row0 + w * 32 + (l >> 3)) * 512 + swz;
  const unsigned short* gsB = Gt + b * 262144 + (col0 + w * 32 + (l >> 3)) * 512 + swz;

  f32x4 acc[4][4] = {};
  stage_tile128(gsA, gsB, As[0], Bs[0], w);
  __syncthreads();
  for (int kt = 0; kt < 7; ++kt) {
    stage_tile128(gsA + (kt + 1) * 64, gsB + (kt + 1) * 64,
                  As[(kt + 1) & 1], Bs[(kt + 1) & 1], w);
    compute_tile128(As[kt & 1], Bs[kt & 1], wr, wc, g, c16, acc);
    __syncthreads();
  }
  compute_tile128(As[1], Bs[1], wr, wc, g, c16, acc);

#pragma unroll
  for (int mi = 0; mi < 4; ++mi)
#pragma unroll
    for (int ni = 0; ni < 4; ++ni) {
      const int colg = col0 + wc * 64 + ni * 16 + c16;
#pragma unroll
      for (int r = 0; r < 4; ++r) {
        const int rowg = row0 + wr * 64 + mi * 16 + g * 4 + r;
        Mb[(b * 512 + rowg) * 512 + colg] = f2bf(acc[mi][ni][r]);
      }
    }
}

// ---------------- K4: y = xb @ M_b^T + b_out (256x256 pipeline) --------------
__launch_bounds__(512, 2)
__global__ void k4_final(const unsigned short* __restrict__ xb,
                         const unsigned short* __restrict__ Mb,
                         const float* __restrict__ bout,
                         float* __restrict__ y) {
  __shared__ __align__(16) unsigned short L[65536];   // 128 KB
  const int bid = (int)blockIdx.x;
  const int wgid = (bid & 7) * 32 + (bid >> 3);       // bijective (256%8==0)
  const int rt = wgid >> 1, ct = wgid & 1;
  const int tid = (int)threadIdx.x;
  const int l = tid & 63, w = tid >> 6;
  const int wr = w >> 2, wc = w & 3;
  const int g = l >> 4, c16 = l & 15;
  const int row0 = rt * 256, col0 = ct * 256;
  const int bb = row0 >> 13;
  const int swzc = ((tid & 7) ^ ((tid >> 3) & 7)) * 8;
  const int r8 = tid >> 3;

  const unsigned short* pA[4];
  const unsigned short* pB[4];
#pragma unroll
  for (int i = 0; i < 4; ++i) {
    pA[i] = xb + (row0 + i * 64 + r8) * 512 + swzc;
    pB[i] = Mb + (bb * 512 + col0 + i * 64 + r8) * 512 + swzc;
  }

  f32x4 acc[8][4] = {};
  gemm256_loop(pA, pB, L, tid, acc);

  float bo[4];
#pragma unroll
  for (int ni = 0; ni < 4; ++ni)
    bo[ni] = bout[col0 + wc * 64 + ni * 16 + c16];
#pragma unroll
  for (int mi = 0; mi < 8; ++mi)
#pragma unroll
    for (int ni = 0; ni < 4; ++ni) {
      const int colg = col0 + wc * 64 + ni * 16 + c16;
#pragma unroll
      for (int r = 0; r < 4; ++r) {
        const int rowg = row0 + wr * 128 + mi * 16 + g * 4 + r;
        y[rowg * 512 + colg] = acc[mi][ni][r] + bo[ni];
      }
    }
}

// ---------------------------------------------------------------------------
extern "C" void kernel_launch(void* const* d_in, const int* in_sizes, int n_in,
                              void* d_out, int out_size, void* d_ws, size_t ws_size,
                              hipStream_t stream) {
  (void)in_sizes; (void)n_in; (void)out_size; (void)ws_size;
  const float* x    = (const float*)d_in[0];
  const float* Wqkv = (const float*)d_in[1];
  const float* gK   = (const float*)d_in[2];
  const float* bK   = (const float*)d_in[3];
  const float* gV   = (const float*)d_in[4];
  const float* bV   = (const float*)d_in[5];
  const float* Wout = (const float*)d_in[6];
  const float* bout = (const float*)d_in[7];
  float* y = (float*)d_out;

  // workspace carve (~40 MB)
  char* w = (char*)d_ws;
  unsigned short* xb  = (unsigned short*)(w);              // 33,554,432
  unsigned short* Wb  = (unsigned short*)(w + 33554432);   //  1,572,864
  unsigned short* Wob = (unsigned short*)(w + 35127296);   //    524,288
  float*          P   = (float*)         (w + 35651584);   //    524,288
  unsigned short* Gt  = (unsigned short*)(w + 36175872);   //  2,097,152
  unsigned short* Mb  = (unsigned short*)(w + 38273024);   //  2,097,152

  k_cvt_bf16<<<16384, 256, 0, stream>>>(x, xb, 4194304);
  k_cvt_bf16<<<768, 256, 0, stream>>>(Wqkv, Wb, 196608);
  k_cvt_bf16<<<256, 256, 0, stream>>>(Wout, Wob, 65536);
  hipMemsetAsync(P, 0, 524288, stream);

  k1_kvp<<<512, 512, 0, stream>>>(xb, Wb, gK, bK, gV, bV, P);
  k3a_g<<<dim3(32, 8), 256, 0, stream>>>(Wqkv, P, Gt);
  k3b_m<<<dim3(4, 4, 4), 256, 0, stream>>>(Wob, Gt, Mb);
  k4_final<<<256, 512, 0, stream>>>(xb, Mb, bout, y);
}

// Round 5
// 130.604 us; speedup vs baseline: 1.2327x; 1.2327x over previous
//
#include <hip/hip_runtime.h>

// ---------------------------------------------------------------------------
// GalerkinAttention on MI355X (gfx950), round 5.
// K1: 256x256 8-wave 4-phase counted-vmcnt pipeline, codegen-hardened:
//     - NO pointer arrays (scalarized pa0..3/pb0..3, arithmetic buffer select)
//     - "memory" clobber on every s_waitcnt asm
//     - longhand phases, sched_barrier(0) after lgkmcnt(0)
// K4: reverted to round-3 128^2 2-phase (isolates the K1 experiment).
//
// Shapes: B=4, N=8192, D=512, H=8, Dh=64. Algebra: y = x @ M_b^T + b_out,
//   M_b[d'][d] = sum_h W_out[d',h-blk] . P_bh . W_q[h-blk,d] / n
//
// MFMA 16x16x32 bf16 (verified r1-4):
//   A frag: lane l holds A[row=l&15][k = ks*32 + (l>>4)*8 + e]
//   B frag: lane l holds B[col=l&15][same k]
//   C/D   : lane l reg r -> C[row=(l>>4)*4+r][col=l&15]
// LDS swizzle (8-short XOR, PMC-verified 0 conflicts in r2):
//   stage src col pre-swizzled ((tid&7)^((tid>>3)&7))*8; read col ^((c16&7)<<3)
// vmcnt ledger (per wave, 2 loads/half-tile): tile T stages A(T+1)@ph0-1,
//   B(T+2)@ph2-3; end-of-T outstanding = 12 -> vmcnt(4) leaves B(T+2) in
//   flight. kt==6 -> vmcnt(0) (no B staged). Never drained mid-tile.
// ---------------------------------------------------------------------------

typedef __attribute__((ext_vector_type(8))) short bf16x8;
typedef __attribute__((ext_vector_type(4))) float f32x4;
typedef __attribute__((ext_vector_type(4))) unsigned short u16x4;

__device__ __forceinline__ unsigned short f2bf(float f) {
  unsigned int u = __builtin_bit_cast(unsigned int, f);
  u += 0x7FFFu + ((u >> 16) & 1u);   // RNE
  return (unsigned short)(u >> 16);
}

__device__ __forceinline__ f32x4 mfma16(bf16x8 a, bf16x8 b, f32x4 c) {
  return __builtin_amdgcn_mfma_f32_16x16x32_bf16(a, b, c, 0, 0, 0);
}

__device__ __forceinline__ void gload16(const void* g, void* l) {
  __builtin_amdgcn_global_load_lds(
      (const __attribute__((address_space(1))) void*)g,
      (__attribute__((address_space(3))) void*)l, 16, 0, 0);
}

// ------------------------------- K0: convert -------------------------------
__global__ void k_cvt_bf16(const float* __restrict__ src,
                           unsigned short* __restrict__ dst, int n4) {
  int i = blockIdx.x * blockDim.x + threadIdx.x;
  if (i < n4) {
    float4 v = ((const float4*)src)[i];
    u16x4 o;
    o[0] = f2bf(v.x); o[1] = f2bf(v.y); o[2] = f2bf(v.z); o[3] = f2bf(v.w);
    ((u16x4*)dst)[i] = o;
  }
}

// ---------------- K1: kv GEMM (256^2 pipelined) + LN + P --------------------
// 1D grid 512 (XCD-bijective swizzle) -> (rt 0..127, ct 0..3); 512 threads.
// Wave quadrant wc: 0=k h0, 1=v h0, 2=k h1, 3=v h1 (h0=2ct, h1=2ct+1).
__launch_bounds__(512, 2)
__global__ void k1_kvp(const unsigned short* __restrict__ xb,
                       const unsigned short* __restrict__ wqkvb,
                       const float* __restrict__ gK, const float* __restrict__ bK,
                       const float* __restrict__ gV, const float* __restrict__ bV,
                       float* __restrict__ P) {
  __shared__ __align__(16) unsigned short L[65536];   // 128 KB
  const int bid = (int)blockIdx.x;
  const int wgid = (bid & 7) * 64 + (bid >> 3);       // bijective (512%8==0)
  const int rt = wgid >> 2, ct = wgid & 3;
  const int tid = (int)threadIdx.x;
  const int l = tid & 63, w = tid >> 6;
  const int wr = w >> 2, wc = w & 3;
  const int g = l >> 4, c16 = l & 15;
  const int row0 = rt * 256;
  const int swzc = ((tid & 7) ^ ((tid >> 3) & 7)) * 8;
  const int r8 = tid >> 3;
  const int wslot = w * 512;

  // scalarized staging pointers (tile-row groups of 64; k=0 column)
  const unsigned short* pa0 = xb + (row0 +   0 + r8) * 512 + swzc;
  const unsigned short* pa1 = xb + (row0 +  64 + r8) * 512 + swzc;
  const unsigned short* pa2 = xb + (row0 + 128 + r8) * 512 + swzc;
  const unsigned short* pa3 = xb + (row0 + 192 + r8) * 512 + swzc;
  const int h0 = 2 * ct, h1 = 2 * ct + 1;
  const unsigned short* pb0 = wqkvb + (512  + h0 * 64 + r8) * 512 + swzc; // k h0
  const unsigned short* pb1 = wqkvb + (1024 + h0 * 64 + r8) * 512 + swzc; // v h0
  const unsigned short* pb2 = wqkvb + (512  + h1 * 64 + r8) * 512 + swzc; // k h1
  const unsigned short* pb3 = wqkvb + (1024 + h1 * 64 + r8) * 512 + swzc; // v h1

  // invariant read offsets
  const int kc0 = (g * 8) ^ ((c16 & 7) << 3);
  const int kc1 = kc0 ^ 32;
  const int abase = (wr * 128 + c16) * 64;   // + row16*1024 + kc
  const int bbase = (wc * 64 + c16) * 64;    // + ni*1024 + kc

  f32x4 acc[8][4] = {};

  // ---- prologue: B(0)x4, A(0)x4, B(1)x4; drain to 4 (B(1) stays in flight)
  gload16(pb0, L + 32768 + 0 * 4096 + wslot);
  gload16(pb1, L + 32768 + 1 * 4096 + wslot);
  gload16(pb2, L + 32768 + 2 * 4096 + wslot);
  gload16(pb3, L + 32768 + 3 * 4096 + wslot);
  gload16(pa0, L + 0 * 4096 + wslot);
  gload16(pa1, L + 1 * 4096 + wslot);
  gload16(pa2, L + 2 * 4096 + wslot);
  gload16(pa3, L + 3 * 4096 + wslot);
  gload16(pb0 + 64, L + 49152 + 0 * 4096 + wslot);
  gload16(pb1 + 64, L + 49152 + 1 * 4096 + wslot);
  gload16(pb2 + 64, L + 49152 + 2 * 4096 + wslot);
  gload16(pb3 + 64, L + 49152 + 3 * 4096 + wslot);
  asm volatile("s_waitcnt vmcnt(4)" ::: "memory");
  __builtin_amdgcn_s_barrier();

  for (int kt = 0; kt < 8; ++kt) {
    const unsigned short* Ab = L + (kt & 1) * 16384;
    const unsigned short* Bb = L + 32768 + (kt & 1) * 16384;
    unsigned short* LAn = L + ((kt + 1) & 1) * 16384;          // A(kt+1)
    unsigned short* LBn = L + 32768 + (kt & 1) * 16384;        // B(kt+2)
    const int koffA = (kt + 1) * 64;
    const int koffB = (kt + 2) * 64;
    bf16x8 bfr[4][2];

    // ================= phase 0: B-frags + A rows 0,1; stage A half0 ========
#pragma unroll
    for (int ni = 0; ni < 4; ++ni) {
      bfr[ni][0] = *(const bf16x8*)&Bb[bbase + ni * 1024 + kc0];
      bfr[ni][1] = *(const bf16x8*)&Bb[bbase + ni * 1024 + kc1];
    }
    {
      bf16x8 a00 = *(const bf16x8*)&Ab[abase + 0 * 1024 + kc0];
      bf16x8 a01 = *(const bf16x8*)&Ab[abase + 0 * 1024 + kc1];
      bf16x8 a10 = *(const bf16x8*)&Ab[abase + 1 * 1024 + kc0];
      bf16x8 a11 = *(const bf16x8*)&Ab[abase + 1 * 1024 + kc1];
      if (kt < 7) {
        gload16(pa0 + koffA, LAn + 0 * 4096 + wslot);
        gload16(pa1 + koffA, LAn + 1 * 4096 + wslot);
      }
      __builtin_amdgcn_s_barrier();
      asm volatile("s_waitcnt lgkmcnt(0)" ::: "memory");
      __builtin_amdgcn_sched_barrier(0);
      __builtin_amdgcn_s_setprio(1);
#pragma unroll
      for (int ni = 0; ni < 4; ++ni) {
        acc[0][ni] = mfma16(a00, bfr[ni][0], acc[0][ni]);
        acc[0][ni] = mfma16(a01, bfr[ni][1], acc[0][ni]);
        acc[1][ni] = mfma16(a10, bfr[ni][0], acc[1][ni]);
        acc[1][ni] = mfma16(a11, bfr[ni][1], acc[1][ni]);
      }
      __builtin_amdgcn_s_setprio(0);
      __builtin_amdgcn_s_barrier();
    }
    // ================= phase 1: A rows 2,3; stage A half1 ==================
    {
      bf16x8 a00 = *(const bf16x8*)&Ab[abase + 2 * 1024 + kc0];
      bf16x8 a01 = *(const bf16x8*)&Ab[abase + 2 * 1024 + kc1];
      bf16x8 a10 = *(const bf16x8*)&Ab[abase + 3 * 1024 + kc0];
      bf16x8 a11 = *(const bf16x8*)&Ab[abase + 3 * 1024 + kc1];
      if (kt < 7) {
        gload16(pa2 + koffA, LAn + 2 * 4096 + wslot);
        gload16(pa3 + koffA, LAn + 3 * 4096 + wslot);
      }
      __builtin_amdgcn_s_barrier();
      asm volatile("s_waitcnt lgkmcnt(0)" ::: "memory");
      __builtin_amdgcn_sched_barrier(0);
      __builtin_amdgcn_s_setprio(1);
#pragma unroll
      for (int ni = 0; ni < 4; ++ni) {
        acc[2][ni] = mfma16(a00, bfr[ni][0], acc[2][ni]);
        acc[2][ni] = mfma16(a01, bfr[ni][1], acc[2][ni]);
        acc[3][ni] = mfma16(a10, bfr[ni][0], acc[3][ni]);
        acc[3][ni] = mfma16(a11, bfr[ni][1], acc[3][ni]);
      }
      __builtin_amdgcn_s_setprio(0);
      __builtin_amdgcn_s_barrier();
    }
    // ================= phase 2: A rows 4,5; stage B(kt+2) half0 ============
    {
      bf16x8 a00 = *(const bf16x8*)&Ab[abase + 4 * 1024 + kc0];
      bf16x8 a01 = *(const bf16x8*)&Ab[abase + 4 * 1024 + kc1];
      bf16x8 a10 = *(const bf16x8*)&Ab[abase + 5 * 1024 + kc0];
      bf16x8 a11 = *(const bf16x8*)&Ab[abase + 5 * 1024 + kc1];
      if (kt < 6) {
        gload16(pb0 + koffB, LBn + 0 * 4096 + wslot);
        gload16(pb1 + koffB, LBn + 1 * 4096 + wslot);
      }
      __builtin_amdgcn_s_barrier();
      asm volatile("s_waitcnt lgkmcnt(0)" ::: "memory");
      __builtin_amdgcn_sched_barrier(0);
      __builtin_amdgcn_s_setprio(1);
#pragma unroll
      for (int ni = 0; ni < 4; ++ni) {
        acc[4][ni] = mfma16(a00, bfr[ni][0], acc[4][ni]);
        acc[4][ni] = mfma16(a01, bfr[ni][1], acc[4][ni]);
        acc[5][ni] = mfma16(a10, bfr[ni][0], acc[5][ni]);
        acc[5][ni] = mfma16(a11, bfr[ni][1], acc[5][ni]);
      }
      __builtin_amdgcn_s_setprio(0);
      __builtin_amdgcn_s_barrier();
    }
    // ================= phase 3: A rows 6,7; stage B half1; vmcnt ===========
    {
      bf16x8 a00 = *(const bf16x8*)&Ab[abase + 6 * 1024 + kc0];
      bf16x8 a01 = *(const bf16x8*)&Ab[abase + 6 * 1024 + kc1];
      bf16x8 a10 = *(const bf16x8*)&Ab[abase + 7 * 1024 + kc0];
      bf16x8 a11 = *(const bf16x8*)&Ab[abase + 7 * 1024 + kc1];
      if (kt < 6) {
        gload16(pb2 + koffB, LBn + 2 * 4096 + wslot);
        gload16(pb3 + koffB, LBn + 3 * 4096 + wslot);
      }
      __builtin_amdgcn_s_barrier();
      asm volatile("s_waitcnt lgkmcnt(0)" ::: "memory");
      __builtin_amdgcn_sched_barrier(0);
      __builtin_amdgcn_s_setprio(1);
#pragma unroll
      for (int ni = 0; ni < 4; ++ni) {
        acc[6][ni] = mfma16(a00, bfr[ni][0], acc[6][ni]);
        acc[6][ni] = mfma16(a01, bfr[ni][1], acc[6][ni]);
        acc[7][ni] = mfma16(a10, bfr[ni][0], acc[7][ni]);
        acc[7][ni] = mfma16(a11, bfr[ni][1], acc[7][ni]);
      }
      __builtin_amdgcn_s_setprio(0);
      if (kt < 6)       { asm volatile("s_waitcnt vmcnt(4)" ::: "memory"); }
      else if (kt == 6) { asm volatile("s_waitcnt vmcnt(0)" ::: "memory"); }
      __builtin_amdgcn_s_barrier();
    }
  }
  __syncthreads();

  // ---- per-head LayerNorm; kn/vn -> LDS quadrants ([64 d][256 n], 16B-XOR)
  const int h = 2 * ct + (wc >> 1);
  const bool isV = wc & 1;
  const float* gamma = isV ? gV : gK;
  const float* beta  = isV ? bV : bK;
  float gm[4], bt[4];
#pragma unroll
  for (int ni = 0; ni < 4; ++ni) {
    gm[ni] = gamma[h * 64 + ni * 16 + c16];
    bt[ni] = beta[h * 64 + ni * 16 + c16];
  }
  unsigned short* Lq = L + wc * 16384;
#pragma unroll
  for (int mi = 0; mi < 8; ++mi) {
    float mean4[4], rs4[4];
#pragma unroll
    for (int r = 0; r < 4; ++r) {
      float a0 = acc[mi][0][r], a1 = acc[mi][1][r];
      float a2 = acc[mi][2][r], a3 = acc[mi][3][r];
      float s1 = a0 + a1 + a2 + a3;
      float s2 = a0 * a0 + a1 * a1 + a2 * a2 + a3 * a3;
#pragma unroll
      for (int m = 1; m <= 8; m <<= 1) {
        s1 += __shfl_xor(s1, m, 64);
        s2 += __shfl_xor(s2, m, 64);
      }
      const float mean = s1 * (1.0f / 64.0f);
      const float var = s2 * (1.0f / 64.0f) - mean * mean;
      mean4[r] = mean;
      rs4[r] = rsqrtf(var + 1e-5f);
    }
    const int n0 = wr * 128 + mi * 16 + g * 4;
#pragma unroll
    for (int ni = 0; ni < 4; ++ni) {
      u16x4 o;
#pragma unroll
      for (int r = 0; r < 4; ++r)
        o[r] = f2bf((acc[mi][ni][r] - mean4[r]) * rs4[r] * gm[ni] + bt[ni]);
      *(u16x4*)&Lq[(ni * 16 + c16) * 256 + (((n0 >> 3) ^ c16) << 3) + (n0 & 7)] = o;
    }
  }
  __syncthreads();

  // ---- P-partial: waves 0-3 -> h0, waves 4-7 -> h1; strip = dh rows
  const int hh = w >> 2;
  const int strip = w & 3;
  const unsigned short* Kq = L + (hh * 2) * 16384;
  const unsigned short* Vq = L + (hh * 2 + 1) * 16384;
  f32x4 pacc[4] = {};
#pragma unroll
  for (int ks = 0; ks < 8; ++ks) {
    const int grp = ((ks * 4 + g) ^ c16) << 3;
    bf16x8 af = *(const bf16x8*)&Kq[(strip * 16 + c16) * 256 + grp];
#pragma unroll
    for (int ni = 0; ni < 4; ++ni) {
      bf16x8 bv = *(const bf16x8*)&Vq[(ni * 16 + c16) * 256 + grp];
      pacc[ni] = mfma16(af, bv, pacc[ni]);
    }
  }
  const int bh = (row0 >> 13) * 8 + 2 * ct + hh;
  float* Pp = P + bh * 4096;
#pragma unroll
  for (int ni = 0; ni < 4; ++ni)
#pragma unroll
    for (int r = 0; r < 4; ++r)
      atomicAdd(&Pp[(strip * 16 + g * 4 + r) * 64 + ni * 16 + c16], pacc[ni][r]);
}

// ----------------------- 128^2 2-phase GEMM pieces --------------------------
__device__ __forceinline__ void stage_tile128(const unsigned short* pa,
                                              const unsigned short* pb,
                                              unsigned short* As, unsigned short* Bs,
                                              int w) {
#pragma unroll
  for (int j = 0; j < 4; ++j) {
    gload16(pa + j * 8 * 512, As + w * 2048 + j * 512);
    gload16(pb + j * 8 * 512, Bs + w * 2048 + j * 512);
  }
}

__device__ __forceinline__ void compute_tile128(const unsigned short* As,
                                                const unsigned short* Bs,
                                                int wr, int wc, int g, int c16,
                                                f32x4 acc[4][4]) {
#pragma unroll
  for (int ks = 0; ks < 2; ++ks) {
    const int kcol = (ks * 32 + g * 8) ^ ((c16 & 7) << 3);
    bf16x8 af[4], bfv[4];
#pragma unroll
    for (int mi = 0; mi < 4; ++mi)
      af[mi] = *(const bf16x8*)&As[(wr * 64 + mi * 16 + c16) * 64 + kcol];
#pragma unroll
    for (int ni = 0; ni < 4; ++ni)
      bfv[ni] = *(const bf16x8*)&Bs[(wc * 64 + ni * 16 + c16) * 64 + kcol];
#pragma unroll
    for (int mi = 0; mi < 4; ++mi)
#pragma unroll
      for (int ni = 0; ni < 4; ++ni)
        acc[mi][ni] = mfma16(af[mi], bfv[ni], acc[mi][ni]);
  }
}

// ------------- K3a: Gt[b][d][h*64+dv] = sum_dh P[bh][dh][dv]*Wq[h*64+dh][d]/n
__launch_bounds__(256)
__global__ void k3a_g(const float* __restrict__ Wqkv,
                      const float* __restrict__ P,
                      unsigned short* __restrict__ Gt) {
  __shared__ float Pl[64 * 64];
  const int bh = blockIdx.x, dd = blockIdx.y;
  const int b = bh >> 3, h = bh & 7;
  const int t = (int)threadIdx.x;
  for (int i = t; i < 1024; i += 256)
    ((float4*)Pl)[i] = ((const float4*)(P + bh * 4096))[i];
  __syncthreads();

  const int qg = t >> 6, dl = t & 63;
  const int d = dd * 64 + dl;
  float acc[16] = {};
  for (int dh = 0; dh < 64; ++dh) {
    const float wq = Wqkv[(h * 64 + dh) * 512 + d];
    const float* pr = &Pl[dh * 64 + qg * 16];
#pragma unroll
    for (int i = 0; i < 16; ++i) acc[i] += pr[i] * wq;
  }
  unsigned short* go = &Gt[(b * 512 + d) * 512 + h * 64 + qg * 16];
#pragma unroll
  for (int i = 0; i < 16; ++i) go[i] = f2bf(acc[i] * (1.0f / 8192.0f));
}

// ----------- K3b: M_b[d'][d] = sum_e Wout[d'][e] * Gt_b[d][e] ---------------
__launch_bounds__(256)
__global__ void k3b_m(const unsigned short* __restrict__ wob,
                      const unsigned short* __restrict__ Gt,
                      unsigned short* __restrict__ Mb) {
  __shared__ __align__(16) unsigned short As[2][8192];
  __shared__ __align__(16) unsigned short Bs[2][8192];
  const int rt = blockIdx.x, ct = blockIdx.y, b = blockIdx.z;
  const int tid = (int)threadIdx.x;
  const int l = tid & 63, w = tid >> 6;
  const int wr = w >> 1, wc = w & 1;
  const int g = l >> 4, c16 = l & 15;
  const int row0 = rt * 128, col0 = ct * 128;
  const int swz = ((l & 7) ^ (l >> 3)) * 8;

  const unsigned short* gsA = wob + (row0 + w * 32 + (l >> 3)) * 512 + swz;
  const unsigned short* gsB = Gt + b * 262144 + (col0 + w * 32 + (l >> 3)) * 512 + swz;

  f32x4 acc[4][4] = {};
  stage_tile128(gsA, gsB, As[0], Bs[0], w);
  __syncthreads();
  for (int kt = 0; kt < 7; ++kt) {
    stage_tile128(gsA + (kt + 1) * 64, gsB + (kt + 1) * 64,
                  As[(kt + 1) & 1], Bs[(kt + 1) & 1], w);
    compute_tile128(As[kt & 1], Bs[kt & 1], wr, wc, g, c16, acc);
    __syncthreads();
  }
  compute_tile128(As[1], Bs[1], wr, wc, g, c16, acc);

#pragma unroll
  for (int mi = 0; mi < 4; ++mi)
#pragma unroll
    for (int ni = 0; ni < 4; ++ni) {
      const int colg = col0 + wc * 64 + ni * 16 + c16;
#pragma unroll
      for (int r = 0; r < 4; ++r) {
        const int rowg = row0 + wr * 64 + mi * 16 + g * 4 + r;
        Mb[(b * 512 + rowg) * 512 + colg] = f2bf(acc[mi][ni][r]);
      }
    }
}

// ---------------- K4: y = xb @ M_b^T + b_out (128^2 2-phase) ----------------
__launch_bounds__(256)
__global__ void k4_final(const unsigned short* __restrict__ xb,
                         const unsigned short* __restrict__ Mb,
                         const float* __restrict__ bout,
                         float* __restrict__ y) {
  __shared__ __align__(16) unsigned short As[2][8192];
  __shared__ __align__(16) unsigned short Bs[2][8192];
  const int rt = blockIdx.x, ct = blockIdx.y;
  const int tid = (int)threadIdx.x;
  const int l = tid & 63, w = tid >> 6;
  const int wr = w >> 1, wc = w & 1;
  const int g = l >> 4, c16 = l & 15;
  const int row0 = rt * 128, col0 = ct * 128;
  const int bb = row0 >> 13;
  const int swz = ((l & 7) ^ (l >> 3)) * 8;

  const unsigned short* gsA = xb + (row0 + w * 32 + (l >> 3)) * 512 + swz;
  const unsigned short* gsB = Mb + bb * 262144 + (col0 + w * 32 + (l >> 3)) * 512 + swz;

  f32x4 acc[4][4] = {};
  stage_tile128(gsA, gsB, As[0], Bs[0], w);
  __syncthreads();
  for (int kt = 0; kt < 7; ++kt) {
    stage_tile128(gsA + (kt + 1) * 64, gsB + (kt + 1) * 64,
                  As[(kt + 1) & 1], Bs[(kt + 1) & 1], w);
    compute_tile128(As[kt & 1], Bs[kt & 1], wr, wc, g, c16, acc);
    __syncthreads();
  }
  compute_tile128(As[1], Bs[1], wr, wc, g, c16, acc);

  float bo[4];
#pragma unroll
  for (int ni = 0; ni < 4; ++ni)
    bo[ni] = bout[col0 + wc * 64 + ni * 16 + c16];
#pragma unroll
  for (int mi = 0; mi < 4; ++mi)
#pragma unroll
    for (int ni = 0; ni < 4; ++ni) {
      const int colg = col0 + wc * 64 + ni * 16 + c16;
#pragma unroll
      for (int r = 0; r < 4; ++r) {
        const int rowg = row0 + wr * 64 + mi * 16 + g * 4 + r;
        y[rowg * 512 + colg] = acc[mi][ni][r] + bo[ni];
      }
    }
}

// ---------------------------------------------------------------------------
extern "C" void kernel_launch(void* const* d_in, const int* in_sizes, int n_in,
                              void* d_out, int out_size, void* d_ws, size_t ws_size,
                              hipStream_t stream) {
  (void)in_sizes; (void)n_in; (void)out_size; (void)ws_size;
  const float* x    = (const float*)d_in[0];
  const float* Wqkv = (const float*)d_in[1];
  const float* gK   = (const float*)d_in[2];
  const float* bK   = (const float*)d_in[3];
  const float* gV   = (const float*)d_in[4];
  const float* bV   = (const float*)d_in[5];
  const float* Wout = (const float*)d_in[6];
  const float* bout = (const float*)d_in[7];
  float* y = (float*)d_out;

  // workspace carve (~40 MB)
  char* w = (char*)d_ws;
  unsigned short* xb  = (unsigned short*)(w);              // 33,554,432
  unsigned short* Wb  = (unsigned short*)(w + 33554432);   //  1,572,864
  unsigned short* Wob = (unsigned short*)(w + 35127296);   //    524,288
  float*          P   = (float*)         (w + 35651584);   //    524,288
  unsigned short* Gt  = (unsigned short*)(w + 36175872);   //  2,097,152
  unsigned short* Mb  = (unsigned short*)(w + 38273024);   //  2,097,152

  k_cvt_bf16<<<16384, 256, 0, stream>>>(x, xb, 4194304);
  k_cvt_bf16<<<768, 256, 0, stream>>>(Wqkv, Wb, 196608);
  k_cvt_bf16<<<256, 256, 0, stream>>>(Wout, Wob, 65536);
  hipMemsetAsync(P, 0, 524288, stream);

  k1_kvp<<<512, 512, 0, stream>>>(xb, Wb, gK, bK, gV, bV, P);
  k3a_g<<<dim3(32, 8), 256, 0, stream>>>(Wqkv, P, Gt);
  k3b_m<<<dim3(4, 4, 4), 256, 0, stream>>>(Wob, Gt, Mb);
  k4_final<<<dim3(256, 4), 256, 0, stream>>>(xb, Mb, bout, y);
}